// Round 8
// baseline (200.996 us; speedup 1.0000x reference)
//
#include <hip/hip_runtime.h>
#include <hip/hip_bf16.h>

#define EPS 1e-5f
#define INV15 (1.0f/15.0f)

#define CIN 64
#define HID 384
#define HW 3136        // 56*56
#define NPIX 100352    // 32*HW
#define BLKPB 1605632  // NPIX*16 bytes per 32-channel block (packed nibbles)
#define NPIXU4 401408  // NPIX*4 uints per 32-channel block

// ws layout (bytes)
#define OFF_BLOB1 0          // 52224: W1frag bf16 [24mt][2ks][64lane][8e] (49152) + sc15[384]f + bi15[384]f
#define OFF_W2PK 52224       // 6912: W2pk[9tap][48g][4j] packed i16x2 weights
#define OFF_A2   59136       // 1536: A2 = s2/15
#define OFF_B2   60672       // 1536: B2 = 15*b2' + 0.5
#define OFF_BLOB3 62208      // 25088: w3 i8 frags [12ks][4nt][64lane][8j] + scale3[64] + bias3[64]
#define OFF_MAX  87296       // 12: uint-as-float max|w|
#define OFF_H1 1048576       // 12 blocks * BLKPB

// merged-kernel LDS layout (uint words): 47872 B -> 3 blocks/CU
#define SH_W2 0        // 2496: W2pk 1728 | A2 384 | B2 384
#define SH_W3 2496     // 6144: w3 i8 frags
#define SH_SC3 8640    // 128: scale3 | bias3
#define SH_H2 8768     // 64 px * 50 w (padded stride vs 48 -> conflict-free)
#define SH_TOT 11968

typedef int v4i __attribute__((ext_vector_type(4)));
typedef float f32x4 __attribute__((ext_vector_type(4)));
typedef short bf16x8 __attribute__((ext_vector_type(8)));

__device__ __forceinline__ short splitbf(float f, float& rem) {
  __hip_bfloat16 h = __float2bfloat16(f);
  rem = f - __bfloat162float(h);
  return __builtin_bit_cast(short, h);
}

__device__ __forceinline__ int pk_mad(unsigned int w, int a, int c) {
  int d;
  asm("v_pk_mad_i16 %0, %1, %2, %3" : "=v"(d) : "v"(w), "v"(a), "v"(c));
  return d;
}

// channel of (group g, pair j, half h) in the nibble-packed layout
__device__ __forceinline__ int ch_of(int g, int j, int h) {
  return 32 * (g >> 2) + 4 * (g & 3) + 16 * (j & 1) + ((j >> 1) & 1) + 2 * h;
}

// 48 blocks: max|w| per tensor (max|tanh w| = tanh(max|w|), tanh monotone odd)
__global__ __launch_bounds__(256) void prep_max(
    const float* __restrict__ w1, const float* __restrict__ w2,
    const float* __restrict__ w3, unsigned int* __restrict__ maxout) {
  int b = blockIdx.x >> 4;
  int sub = blockIdx.x & 15;
  const float* src = (b == 0) ? w1 : (b == 1) ? w2 : w3;
  int n = (b == 1) ? HID * 9 : HID * CIN;
  float m = 0.f;
  for (int i = sub * 256 + threadIdx.x; i < n; i += 4096)
    m = fmaxf(m, fabsf(src[i]));
  #pragma unroll
  for (int off = 32; off > 0; off >>= 1)
    m = fmaxf(m, __shfl_down(m, off, 64));
  __shared__ float red[4];
  if ((threadIdx.x & 63) == 0) red[threadIdx.x >> 6] = m;
  __syncthreads();
  if (threadIdx.x == 0) {
    m = fmaxf(fmaxf(red[0], red[1]), fmaxf(red[2], red[3]));
    atomicMax(maxout + b, __float_as_uint(m));
  }
}

// builds all folded/permuted weight blobs. 52544 ids -> 206 blocks.
__global__ __launch_bounds__(256) void prep_quant(
    const float* __restrict__ w1, const float* __restrict__ w2,
    const float* __restrict__ w3,
    const float* __restrict__ g1, const float* __restrict__ b1,
    const float* __restrict__ m1, const float* __restrict__ v1,
    const float* __restrict__ g2, const float* __restrict__ b2,
    const float* __restrict__ m2, const float* __restrict__ v2,
    const float* __restrict__ g3, const float* __restrict__ b3,
    const float* __restrict__ m3, const float* __restrict__ v3,
    char* __restrict__ ws) {
  const float* maxv = (const float*)(ws + OFF_MAX);
  int idx = blockIdx.x * 256 + threadIdx.x;
  if (idx < 24576) {                      // W1frag bf16 (exact odd ints -15..15)
    float mm = tanhf(maxv[0]);
    int e = idx & 7, lane = (idx >> 3) & 63, ks = (idx >> 9) & 1, mt = idx >> 10;
    int o = mt * 16 + (lane & 15);
    int k = ks * 32 + (lane >> 4) * 8 + e;
    float t = tanhf(w1[o * 64 + k]);
    int wi = 2 * (int)rintf((t / (2.f * mm) + 0.5f) * 15.f) - 15;
    float rr;
    ((short*)(ws + OFF_BLOB1))[idx] = splitbf((float)wi, rr);
  } else if (idx < 26304) {               // W2pk packed i16x2 integer weights
    float mm = tanhf(maxv[1]);
    int jj = idx - 24576;
    int tap = jj / 192, rem = jj - tap * 192;
    int g = rem >> 2, j = rem & 3;
    int clo = ch_of(g, j, 0), chi = ch_of(g, j, 1);
    int wlo = 2 * (int)rintf((tanhf(w2[clo * 9 + tap]) / (2.f * mm) + 0.5f) * 15.f) - 15;
    int whi = 2 * (int)rintf((tanhf(w2[chi * 9 + tap]) / (2.f * mm) + 0.5f) * 15.f) - 15;
    ((unsigned int*)(ws + OFF_W2PK))[jj] =
        ((unsigned int)(unsigned short)(short)wlo) |
        (((unsigned int)(unsigned short)(short)whi) << 16);
  } else if (idx < 26688) {               // A2 = s2/15
    int ii = idx - 26304;
    int g = ii >> 3, j = (ii >> 1) & 3, h = ii & 1;
    int c = ch_of(g, j, h);
    float s = g2[c] / sqrtf(v2[c] + EPS);
    ((float*)(ws + OFF_A2))[ii] = s * (1.f / 15.f);
  } else if (idx < 27072) {               // B2 = 15*b2' + 0.5
    int ii = idx - 26688;
    int g = ii >> 3, j = (ii >> 1) & 3, h = ii & 1;
    int c = ch_of(g, j, h);
    float s = g2[c] / sqrtf(v2[c] + EPS);
    ((float*)(ws + OFF_B2))[ii] = 15.f * (b2[c] - m2[c] * s) + 0.5f;
  } else if (idx < 27456) {               // sc15 = s1
    int o = idx - 27072;
    ((float*)(ws + OFF_BLOB1 + 49152))[o] = g1[o] / sqrtf(v1[o] + EPS);
  } else if (idx < 27840) {               // bi15 = 15*(b1 - m1*s1)
    int o = idx - 27456;
    float s = g1[o] / sqrtf(v1[o] + EPS);
    ((float*)(ws + OFF_BLOB1 + 50688))[o] = 15.f * (b1[o] - m1[o] * s);
  } else if (idx < 52416) {               // w3 i8 frags, nibble-permuted k
    float mm = tanhf(maxv[2]);
    int jj = idx - 27840;
    int j = jj & 7, lane = (jj >> 3) & 63, nt = (jj >> 9) & 3, ks = jj >> 11;
    int n = nt * 16 + (lane & 15);
    int quad = lane >> 4;
    int k = ks * 32 + ((j & 1) ? (16 + quad * 4 + (j >> 1)) : (quad * 4 + (j >> 1)));
    float t = tanhf(w3[n * 384 + k]);
    int wi = 2 * (int)rintf((t / (2.f * mm) + 0.5f) * 15.f) - 15;
    (ws + OFF_BLOB3)[jj] = (char)wi;
  } else if (idx < 52480) {               // scale3 = s3/225
    int n = idx - 52416;
    float s = g3[n] / sqrtf(v3[n] + EPS);
    *(float*)(ws + OFF_BLOB3 + 24576 + n * 4) = s * (1.f / 225.f);
  } else if (idx < 52544) {               // bias3
    int n = idx - 52480;
    float s = g3[n] / sqrtf(v3[n] + EPS);
    *(float*)(ws + OFF_BLOB3 + 24832 + n * 4) = b3[n] - m3[n] * s;
  }
}

// conv1 1x1 (64->384) via bf16 MFMA (x = hi+lo+lo2, exact int weights) + bn + relu
// + act_quant -> packed nibbles. grid 784 blocks x 128 px; wave = 16 px x 2 tiles.
__global__ __launch_bounds__(256) void k1(
    const float* __restrict__ x, const char* __restrict__ blob1,
    char* __restrict__ h1b) {
  __shared__ uint4 sBuf[3264];    // 49152B wfrags + 1536B sc15 + 1536B bi15
  int tid = threadIdx.x;
  {
    const uint4* src = (const uint4*)blob1;
    for (int i = tid; i < 3264; i += 256) sBuf[i] = src[i];
  }
  __syncthreads();
  const bf16x8* wf = (const bf16x8*)sBuf;
  const float* sSB = (const float*)(sBuf + 3072);   // [0..383]=sc15, [384..767]=bi15

  int wv = tid >> 6, lane = tid & 63;
  int quad = lane >> 4, m = lane & 15;

  for (int t = 0; t < 2; t++) {
    int grp = blockIdx.x * 8 + t * 4 + wv;          // 16-px group, 0..6271
    size_t pixabs = (size_t)grp * 16 + m;
    int img = grp / 196;                            // 196 groups per image
    int prem = (grp - img * 196) * 16 + m;
    const float* xb = x + (size_t)img * (CIN * HW) + prem;

    bf16x8 xh[2], xl[2], xq[2];
    #pragma unroll
    for (int ks = 0; ks < 2; ks++) {
      #pragma unroll
      for (int e = 0; e < 8; e++) {
        float f = xb[(size_t)(ks * 32 + quad * 8 + e) * HW];
        float r1, r2, r3;
        xh[ks][e] = splitbf(f, r1);
        xl[ks][e] = splitbf(r1, r2);
        xq[ks][e] = splitbf(r2, r3);
      }
    }

    #pragma unroll
    for (int half = 0; half < 2; half++) {
      f32x4 acc[12];
      #pragma unroll
      for (int i = 0; i < 12; i++) { f32x4 z = {0.f, 0.f, 0.f, 0.f}; acc[i] = z; }
      #pragma unroll
      for (int i = 0; i < 12; i++) {
        int mt = half * 12 + i;
        bf16x8 w0 = wf[(mt * 2 + 0) * 64 + lane];
        bf16x8 w1 = wf[(mt * 2 + 1) * 64 + lane];
        acc[i] = __builtin_amdgcn_mfma_f32_16x16x32_bf16(w0, xh[0], acc[i], 0, 0, 0);
        acc[i] = __builtin_amdgcn_mfma_f32_16x16x32_bf16(w1, xh[1], acc[i], 0, 0, 0);
        acc[i] = __builtin_amdgcn_mfma_f32_16x16x32_bf16(w0, xl[0], acc[i], 0, 0, 0);
        acc[i] = __builtin_amdgcn_mfma_f32_16x16x32_bf16(w1, xl[1], acc[i], 0, 0, 0);
        acc[i] = __builtin_amdgcn_mfma_f32_16x16x32_bf16(w0, xq[0], acc[i], 0, 0, 0);
        acc[i] = __builtin_amdgcn_mfma_f32_16x16x32_bf16(w1, xq[1], acc[i], 0, 0, 0);
      }
      #pragma unroll
      for (int l = 0; l < 6; l++) {
        int b = half * 6 + l;
        f32x4 ae = acc[2 * l], ao = acc[2 * l + 1];
        unsigned int pk = 0;
        #pragma unroll
        for (int r = 0; r < 4; r++) {
          int oe = 32 * b + quad * 4 + r;
          int oo = oe + 16;
          float fe = fminf(fmaxf(ae[r] * sSB[oe] + sSB[384 + oe], 0.f), 15.f);
          float fo = fminf(fmaxf(ao[r] * sSB[oo] + sSB[384 + oo], 0.f), 15.f);
          pk |= ((unsigned int)(int)rintf(fe)) << (8 * r);
          pk |= ((unsigned int)(int)rintf(fo)) << (8 * r + 4);
        }
        *(unsigned int*)(h1b + (size_t)b * BLKPB + pixabs * 16 + quad * 4) = pk;
      }
    }
  }
}

// Merged dw3x3(pk_mad, h2 -> LDS) + conv3(i8 MFMA) + bn + act_quant + residual.
// grid 1568: one block = 64 px of one image.
__global__ __launch_bounds__(256) void InvertedBottleneck_conv_Q_13709535609694_kernel(
    const unsigned int* __restrict__ h1q, const char* __restrict__ ws,
    const float* __restrict__ x, float* __restrict__ out) {
  __shared__ unsigned int sh[SH_TOT];
  int tid = threadIdx.x;
  {
    const unsigned int* s2 = (const unsigned int*)(ws + OFF_W2PK);
    for (int i = tid; i < 2496; i += 256) sh[SH_W2 + i] = s2[i];
    const unsigned int* s3 = (const unsigned int*)(ws + OFF_BLOB3);
    for (int i = tid; i < 6272; i += 256) sh[SH_W3 + i] = s3[i];  // frags + scales
  }
  __syncthreads();

  int img = blockIdx.x / 49;
  int trem = blockIdx.x - img * 49;
  size_t imgrow = (size_t)img * HW;

  // ---- Phase B: depthwise 3x3 via pk_mad -> h2 tile in LDS ----
  {
    const uint4* W4 = (const uint4*)&sh[SH_W2];
    const float* Af = (const float*)&sh[SH_W2 + 1728];
    const float* Bf = Af + 384;
    #pragma unroll
    for (int it2 = 0; it2 < 3; it2++) {
      int id = it2 * 256 + tid;          // 768 = 48 g x 16 quads
      int gg = id % 48, q4 = id / 48;
      int prem = trem * 64 + q4 * 4;
      int h = prem / 56, w0 = prem - h * 56;   // 4-px quad never crosses a row (56%4==0)
      size_t base_u = (size_t)(gg >> 2) * NPIXU4 + (gg & 3);
      int acc2[4][4];
      #pragma unroll
      for (int p = 0; p < 4; p++)
        #pragma unroll
        for (int j = 0; j < 4; j++) acc2[p][j] = 0;
      #pragma unroll
      for (int dh = 0; dh < 3; dh++) {
        int hr = h + dh - 1;
        bool vrow = (unsigned)hr < 56u;
        const unsigned int* rp = h1q + base_u + (imgrow + (size_t)hr * 56) * 4;
        int P[6][4];
        #pragma unroll
        for (int c = 0; c < 6; c++) {
          int wc = w0 + c - 1;
          unsigned int u = 0;
          if (vrow && (unsigned)wc < 56u) u = rp[(size_t)wc * 4];
          P[c][0] = (int)(u & 0x000F000Fu);
          P[c][1] = (int)((u >> 4) & 0x000F000Fu);
          P[c][2] = (int)((u >> 8) & 0x000F000Fu);
          P[c][3] = (int)((u >> 12) & 0x000F000Fu);
        }
        #pragma unroll
        for (int cw = 0; cw < 3; cw++) {
          uint4 wvv = W4[(dh * 3 + cw) * 48 + gg];
          #pragma unroll
          for (int p = 0; p < 4; p++) {
            acc2[p][0] = pk_mad(wvv.x, P[p + cw][0], acc2[p][0]);
            acc2[p][1] = pk_mad(wvv.y, P[p + cw][1], acc2[p][1]);
            acc2[p][2] = pk_mad(wvv.z, P[p + cw][2], acc2[p][2]);
            acc2[p][3] = pk_mad(wvv.w, P[p + cw][3], acc2[p][3]);
          }
        }
      }
      float Ar[8], Br[8];
      #pragma unroll
      for (int i = 0; i < 8; i++) { Ar[i] = Af[gg * 8 + i]; Br[i] = Bf[gg * 8 + i]; }
      #pragma unroll
      for (int p = 0; p < 4; p++) {
        unsigned int pk = 0;
        #pragma unroll
        for (int j = 0; j < 4; j++) {
          int a = acc2[p][j];
          int lo = (a << 16) >> 16;
          int hi = a >> 16;
          float vl = fmaf((float)lo, Ar[2 * j], Br[2 * j]);
          float vh = fmaf((float)hi, Ar[2 * j + 1], Br[2 * j + 1]);
          unsigned int ql = (unsigned int)fmaxf(fminf(vl, 15.49f), 0.f);
          unsigned int qh = (unsigned int)fmaxf(fminf(vh, 15.49f), 0.f);
          pk |= ql << (4 * j);
          pk |= qh << (4 * j + 16);
        }
        sh[SH_H2 + (q4 * 4 + p) * 50 + gg] = pk;
      }
    }
  }
  __syncthreads();

  // ---- Phase C: conv3 1x1 (384->64) i8 MFMA + bn + act_quant + residual ----
  {
    int wv = tid >> 6, lane = tid & 63;
    int m = lane & 15, quad = lane >> 4;
    const long* sh8 = (const long*)&sh[SH_W3];
    const float* scl = (const float*)&sh[SH_SC3];
    int px_local = wv * 16 + m;

    unsigned int ua[12];
    #pragma unroll
    for (int ks = 0; ks < 12; ks++) ua[ks] = sh[SH_H2 + px_local * 50 + ks * 4 + quad];

    v4i acc3[4];
    #pragma unroll
    for (int nt = 0; nt < 4; nt++) { v4i z = {0, 0, 0, 0}; acc3[nt] = z; }

    #pragma unroll
    for (int ks = 0; ks < 12; ks++) {
      unsigned int u = ua[ks];
      unsigned int tt = u & 0x0F0F0F0Fu;
      unsigned int ss = (u >> 4) & 0x0F0F0F0Fu;
      unsigned int d0 = (tt & 0xFFu) | ((ss & 0xFFu) << 8) | ((tt & 0xFF00u) << 8) | ((ss & 0xFF00u) << 16);
      unsigned int d1 = ((tt >> 16) & 0xFFu) | (((ss >> 16) & 0xFFu) << 8) | ((tt >> 24) << 16) | ((ss >> 24) << 24);
      long aF = (long)(((unsigned long)d1 << 32) | (unsigned long)d0);
      #pragma unroll
      for (int nt = 0; nt < 4; nt++) {
        long bF = sh8[(ks * 4 + nt) * 64 + lane];
        acc3[nt] = __builtin_amdgcn_mfma_i32_16x16x32_i8(aF, bF, acc3[nt], 0, 0, 0);
      }
    }

    int prem = trem * 64 + wv * 16 + quad * 4;
    #pragma unroll
    for (int nt = 0; nt < 4; nt++) {
      int n = nt * 16 + m;
      float sc = scl[n];
      float bi = scl[64 + n];
      size_t off = ((size_t)img * CIN + n) * HW + prem;
      const float4 xv = *(const float4*)(x + off);
      float4 ov;
      float v, a;
      v = (float)acc3[nt][0] * sc + bi; a = fminf(fmaxf(v, 0.f), 1.f); ov.x = rintf(a * 15.f) * INV15 + xv.x;
      v = (float)acc3[nt][1] * sc + bi; a = fminf(fmaxf(v, 0.f), 1.f); ov.y = rintf(a * 15.f) * INV15 + xv.y;
      v = (float)acc3[nt][2] * sc + bi; a = fminf(fmaxf(v, 0.f), 1.f); ov.z = rintf(a * 15.f) * INV15 + xv.z;
      v = (float)acc3[nt][3] * sc + bi; a = fminf(fmaxf(v, 0.f), 1.f); ov.w = rintf(a * 15.f) * INV15 + xv.w;
      *(float4*)(out + off) = ov;
    }
  }
}

extern "C" void kernel_launch(void* const* d_in, const int* in_sizes, int n_in,
                              void* d_out, int out_size, void* d_ws, size_t ws_size,
                              hipStream_t stream) {
  const float* x  = (const float*)d_in[0];
  const float* w1 = (const float*)d_in[1];
  const float* w2 = (const float*)d_in[2];
  const float* w3 = (const float*)d_in[3];
  const float* g1 = (const float*)d_in[4];
  const float* b1 = (const float*)d_in[5];
  const float* m1 = (const float*)d_in[6];
  const float* v1 = (const float*)d_in[7];
  const float* g2 = (const float*)d_in[8];
  const float* b2 = (const float*)d_in[9];
  const float* m2 = (const float*)d_in[10];
  const float* v2 = (const float*)d_in[11];
  const float* g3 = (const float*)d_in[12];
  const float* b3 = (const float*)d_in[13];
  const float* m3 = (const float*)d_in[14];
  const float* v3 = (const float*)d_in[15];

  char* ws = (char*)d_ws;
  unsigned int* maxu = (unsigned int*)(ws + OFF_MAX);
  char* h1b = ws + OFF_H1;
  float* outp = (float*)d_out;

  hipMemsetAsync(maxu, 0, 12, stream);
  prep_max<<<dim3(48), dim3(256), 0, stream>>>(w1, w2, w3, maxu);
  prep_quant<<<dim3(206), dim3(256), 0, stream>>>(
      w1, w2, w3, g1, b1, m1, v1, g2, b2, m2, v2, g3, b3, m3, v3, ws);
  k1<<<dim3(784), dim3(256), 0, stream>>>(x, ws + OFF_BLOB1, h1b);
  InvertedBottleneck_conv_Q_13709535609694_kernel<<<dim3(1568), dim3(256), 0, stream>>>(
      (const unsigned int*)h1b, ws, x, outp);
}

// Round 9
// 169.048 us; speedup vs baseline: 1.1890x; 1.1890x over previous
//
#include <hip/hip_runtime.h>
#include <hip/hip_bf16.h>

#define EPS 1e-5f
#define INV15 (1.0f/15.0f)

#define CIN 64
#define HID 384
#define HW 3136        // 56*56
#define NPIX 100352    // 32*HW
#define BLKPB 1605632  // NPIX*16 bytes per 32-channel block (packed nibbles)
#define NPIXU4 401408  // NPIX*4 uints per 32-channel block

// ws layout (bytes)
#define OFF_BLOB1 0          // 52224: W1frag bf16 [24mt][2ks][64lane][8e] (49152) + sc15[384]f + bi15[384]f
#define OFF_W2PK 52224       // 6912: W2pk[9tap][48g][4j] packed i16x2 weights
#define OFF_A2   59136       // 1536: A2 = s2/15
#define OFF_B2   60672       // 1536: B2 = 15*b2' + 0.5
#define OFF_BLOB3 62208      // 25088: w3 i8 frags [12ks][4nt][64lane][8j] + scale3[64] + bias3[64]
#define OFF_MAX  87296       // 12: uint-as-float max|w|
#define OFF_H1 1048576       // 12 blocks * BLKPB

// merged-kernel LDS layout (uint words): 47872 B -> 3 blocks/CU
#define SH_W2 0        // 2496: W2pk 1728 | A2 384 | B2 384
#define SH_W3 2496     // 6144: w3 i8 frags
#define SH_SC3 8640    // 128: scale3 | bias3
#define SH_H2 8768     // 64 px * 50 w (padded stride vs 48 -> conflict-free)
#define SH_TOT 11968

typedef int v4i __attribute__((ext_vector_type(4)));
typedef float f32x4 __attribute__((ext_vector_type(4)));
typedef short bf16x8 __attribute__((ext_vector_type(8)));

__device__ __forceinline__ short splitbf(float f, float& rem) {
  __hip_bfloat16 h = __float2bfloat16(f);
  rem = f - __bfloat162float(h);
  return __builtin_bit_cast(short, h);
}

__device__ __forceinline__ int pk_mad(unsigned int w, int a, int c) {
  int d;
  asm("v_pk_mad_i16 %0, %1, %2, %3" : "=v"(d) : "v"(w), "v"(a), "v"(c));
  return d;
}

// channel of (group g, pair j, half h) in the nibble-packed layout
__device__ __forceinline__ int ch_of(int g, int j, int h) {
  return 32 * (g >> 2) + 4 * (g & 3) + 16 * (j & 1) + ((j >> 1) & 1) + 2 * h;
}

// 48 blocks: max|w| per tensor (max|tanh w| = tanh(max|w|), tanh monotone odd)
__global__ __launch_bounds__(256) void prep_max(
    const float* __restrict__ w1, const float* __restrict__ w2,
    const float* __restrict__ w3, unsigned int* __restrict__ maxout) {
  int b = blockIdx.x >> 4;
  int sub = blockIdx.x & 15;
  const float* src = (b == 0) ? w1 : (b == 1) ? w2 : w3;
  int n = (b == 1) ? HID * 9 : HID * CIN;
  float m = 0.f;
  for (int i = sub * 256 + threadIdx.x; i < n; i += 4096)
    m = fmaxf(m, fabsf(src[i]));
  #pragma unroll
  for (int off = 32; off > 0; off >>= 1)
    m = fmaxf(m, __shfl_down(m, off, 64));
  __shared__ float red[4];
  if ((threadIdx.x & 63) == 0) red[threadIdx.x >> 6] = m;
  __syncthreads();
  if (threadIdx.x == 0) {
    m = fmaxf(fmaxf(red[0], red[1]), fmaxf(red[2], red[3]));
    atomicMax(maxout + b, __float_as_uint(m));
  }
}

// builds all folded/permuted weight blobs. 52544 ids -> 206 blocks.
__global__ __launch_bounds__(256) void prep_quant(
    const float* __restrict__ w1, const float* __restrict__ w2,
    const float* __restrict__ w3,
    const float* __restrict__ g1, const float* __restrict__ b1,
    const float* __restrict__ m1, const float* __restrict__ v1,
    const float* __restrict__ g2, const float* __restrict__ b2,
    const float* __restrict__ m2, const float* __restrict__ v2,
    const float* __restrict__ g3, const float* __restrict__ b3,
    const float* __restrict__ m3, const float* __restrict__ v3,
    char* __restrict__ ws) {
  const float* maxv = (const float*)(ws + OFF_MAX);
  int idx = blockIdx.x * 256 + threadIdx.x;
  if (idx < 24576) {                      // W1frag bf16 (exact odd ints -15..15)
    float mm = tanhf(maxv[0]);
    int e = idx & 7, lane = (idx >> 3) & 63, ks = (idx >> 9) & 1, mt = idx >> 10;
    int o = mt * 16 + (lane & 15);
    int k = ks * 32 + (lane >> 4) * 8 + e;
    float t = tanhf(w1[o * 64 + k]);
    int wi = 2 * (int)rintf((t / (2.f * mm) + 0.5f) * 15.f) - 15;
    float rr;
    ((short*)(ws + OFF_BLOB1))[idx] = splitbf((float)wi, rr);
  } else if (idx < 26304) {               // W2pk packed i16x2 integer weights
    float mm = tanhf(maxv[1]);
    int jj = idx - 24576;
    int tap = jj / 192, rem = jj - tap * 192;
    int g = rem >> 2, j = rem & 3;
    int clo = ch_of(g, j, 0), chi = ch_of(g, j, 1);
    int wlo = 2 * (int)rintf((tanhf(w2[clo * 9 + tap]) / (2.f * mm) + 0.5f) * 15.f) - 15;
    int whi = 2 * (int)rintf((tanhf(w2[chi * 9 + tap]) / (2.f * mm) + 0.5f) * 15.f) - 15;
    ((unsigned int*)(ws + OFF_W2PK))[jj] =
        ((unsigned int)(unsigned short)(short)wlo) |
        (((unsigned int)(unsigned short)(short)whi) << 16);
  } else if (idx < 26688) {               // A2 = s2/15
    int ii = idx - 26304;
    int g = ii >> 3, j = (ii >> 1) & 3, h = ii & 1;
    int c = ch_of(g, j, h);
    float s = g2[c] / sqrtf(v2[c] + EPS);
    ((float*)(ws + OFF_A2))[ii] = s * (1.f / 15.f);
  } else if (idx < 27072) {               // B2 = 15*b2' + 0.5
    int ii = idx - 26688;
    int g = ii >> 3, j = (ii >> 1) & 3, h = ii & 1;
    int c = ch_of(g, j, h);
    float s = g2[c] / sqrtf(v2[c] + EPS);
    ((float*)(ws + OFF_B2))[ii] = 15.f * (b2[c] - m2[c] * s) + 0.5f;
  } else if (idx < 27456) {               // sc15 = s1
    int o = idx - 27072;
    ((float*)(ws + OFF_BLOB1 + 49152))[o] = g1[o] / sqrtf(v1[o] + EPS);
  } else if (idx < 27840) {               // bi15 = 15*(b1 - m1*s1)
    int o = idx - 27456;
    float s = g1[o] / sqrtf(v1[o] + EPS);
    ((float*)(ws + OFF_BLOB1 + 50688))[o] = 15.f * (b1[o] - m1[o] * s);
  } else if (idx < 52416) {               // w3 i8 frags, nibble-permuted k
    float mm = tanhf(maxv[2]);
    int jj = idx - 27840;
    int j = jj & 7, lane = (jj >> 3) & 63, nt = (jj >> 9) & 3, ks = jj >> 11;
    int n = nt * 16 + (lane & 15);
    int quad = lane >> 4;
    int k = ks * 32 + ((j & 1) ? (16 + quad * 4 + (j >> 1)) : (quad * 4 + (j >> 1)));
    float t = tanhf(w3[n * 384 + k]);
    int wi = 2 * (int)rintf((t / (2.f * mm) + 0.5f) * 15.f) - 15;
    (ws + OFF_BLOB3)[jj] = (char)wi;
  } else if (idx < 52480) {               // scale3 = s3/225
    int n = idx - 52416;
    float s = g3[n] / sqrtf(v3[n] + EPS);
    *(float*)(ws + OFF_BLOB3 + 24576 + n * 4) = s * (1.f / 225.f);
  } else if (idx < 52544) {               // bias3
    int n = idx - 52480;
    float s = g3[n] / sqrtf(v3[n] + EPS);
    *(float*)(ws + OFF_BLOB3 + 24832 + n * 4) = b3[n] - m3[n] * s;
  }
}

// conv1 1x1 (64->384) via bf16 MFMA (x = hi+lo+lo2, exact int weights) + bn + relu
// + act_quant -> packed nibbles. grid 1568 x 64 px; wave = 16 px.
// __launch_bounds__(256,3): cap regs ~168 -> 3 blocks/CU (round-8's 240-VGPR/2-block
// config stalled at 8% occupancy).
__global__ __launch_bounds__(256, 3) void k1(
    const float* __restrict__ x, const char* __restrict__ blob1,
    char* __restrict__ h1b) {
  __shared__ uint4 sBuf[3264];    // 49152B wfrags + 1536B sc15 + 1536B bi15
  int tid = threadIdx.x;
  {
    const uint4* src = (const uint4*)blob1;
    for (int i = tid; i < 3264; i += 256) sBuf[i] = src[i];
  }
  __syncthreads();
  const bf16x8* wf = (const bf16x8*)sBuf;
  const float* sSB = (const float*)(sBuf + 3072);   // [0..383]=sc15, [384..767]=bi15

  int wv = tid >> 6, lane = tid & 63;
  int quad = lane >> 4, m = lane & 15;

  int grp = blockIdx.x * 4 + wv;                  // 16-px group, 0..6271
  size_t pixabs = (size_t)grp * 16 + m;
  int img = grp / 196;                            // 196 groups per image
  int prem = (grp - img * 196) * 16 + m;
  const float* xb = x + (size_t)img * (CIN * HW) + prem;

  bf16x8 xh[2], xl[2], xq[2];
  #pragma unroll
  for (int ks = 0; ks < 2; ks++) {
    #pragma unroll
    for (int e = 0; e < 8; e++) {
      float f = xb[(size_t)(ks * 32 + quad * 8 + e) * HW];
      float r1, r2, r3;
      xh[ks][e] = splitbf(f, r1);
      xl[ks][e] = splitbf(r1, r2);
      xq[ks][e] = splitbf(r2, r3);
    }
  }

  #pragma unroll
  for (int half = 0; half < 2; half++) {
    f32x4 acc[12];
    #pragma unroll
    for (int i = 0; i < 12; i++) { f32x4 z = {0.f, 0.f, 0.f, 0.f}; acc[i] = z; }
    #pragma unroll
    for (int i = 0; i < 12; i++) {
      int mt = half * 12 + i;
      bf16x8 w0 = wf[(mt * 2 + 0) * 64 + lane];
      bf16x8 w1 = wf[(mt * 2 + 1) * 64 + lane];
      acc[i] = __builtin_amdgcn_mfma_f32_16x16x32_bf16(w0, xh[0], acc[i], 0, 0, 0);
      acc[i] = __builtin_amdgcn_mfma_f32_16x16x32_bf16(w1, xh[1], acc[i], 0, 0, 0);
      acc[i] = __builtin_amdgcn_mfma_f32_16x16x32_bf16(w0, xl[0], acc[i], 0, 0, 0);
      acc[i] = __builtin_amdgcn_mfma_f32_16x16x32_bf16(w1, xl[1], acc[i], 0, 0, 0);
      acc[i] = __builtin_amdgcn_mfma_f32_16x16x32_bf16(w0, xq[0], acc[i], 0, 0, 0);
      acc[i] = __builtin_amdgcn_mfma_f32_16x16x32_bf16(w1, xq[1], acc[i], 0, 0, 0);
    }
    #pragma unroll
    for (int l = 0; l < 6; l++) {
      int b = half * 6 + l;
      f32x4 ae = acc[2 * l], ao = acc[2 * l + 1];
      unsigned int pk = 0;
      #pragma unroll
      for (int r = 0; r < 4; r++) {
        int oe = 32 * b + quad * 4 + r;
        int oo = oe + 16;
        float fe = fminf(fmaxf(ae[r] * sSB[oe] + sSB[384 + oe], 0.f), 15.f);
        float fo = fminf(fmaxf(ao[r] * sSB[oo] + sSB[384 + oo], 0.f), 15.f);
        pk |= ((unsigned int)(int)rintf(fe)) << (8 * r);
        pk |= ((unsigned int)(int)rintf(fo)) << (8 * r + 4);
      }
      *(unsigned int*)(h1b + (size_t)b * BLKPB + pixabs * 16 + quad * 4) = pk;
    }
  }
}

// Merged dw3x3(pk_mad, h2 -> LDS) + conv3(i8 MFMA) + bn + act_quant + residual.
// grid 1568: one block = 64 px of one image.
__global__ __launch_bounds__(256) void InvertedBottleneck_conv_Q_13709535609694_kernel(
    const unsigned int* __restrict__ h1q, const char* __restrict__ ws,
    const float* __restrict__ x, float* __restrict__ out) {
  __shared__ unsigned int sh[SH_TOT];
  int tid = threadIdx.x;
  {
    const unsigned int* s2 = (const unsigned int*)(ws + OFF_W2PK);
    for (int i = tid; i < 2496; i += 256) sh[SH_W2 + i] = s2[i];
    const unsigned int* s3 = (const unsigned int*)(ws + OFF_BLOB3);
    for (int i = tid; i < 6272; i += 256) sh[SH_W3 + i] = s3[i];  // frags + scales
  }
  __syncthreads();

  int img = blockIdx.x / 49;
  int trem = blockIdx.x - img * 49;
  size_t imgrow = (size_t)img * HW;

  // ---- Phase B: depthwise 3x3 via pk_mad -> h2 tile in LDS ----
  {
    const uint4* W4 = (const uint4*)&sh[SH_W2];
    const float* Af = (const float*)&sh[SH_W2 + 1728];
    const float* Bf = Af + 384;
    #pragma unroll
    for (int it2 = 0; it2 < 3; it2++) {
      int id = it2 * 256 + tid;          // 768 = 48 g x 16 quads
      int gg = id % 48, q4 = id / 48;
      int prem = trem * 64 + q4 * 4;
      int h = prem / 56, w0 = prem - h * 56;   // 4-px quad never crosses a row (56%4==0)
      size_t base_u = (size_t)(gg >> 2) * NPIXU4 + (gg & 3);
      int acc2[4][4];
      #pragma unroll
      for (int p = 0; p < 4; p++)
        #pragma unroll
        for (int j = 0; j < 4; j++) acc2[p][j] = 0;
      #pragma unroll
      for (int dh = 0; dh < 3; dh++) {
        int hr = h + dh - 1;
        bool vrow = (unsigned)hr < 56u;
        const unsigned int* rp = h1q + base_u + (imgrow + (size_t)hr * 56) * 4;
        int P[6][4];
        #pragma unroll
        for (int c = 0; c < 6; c++) {
          int wc = w0 + c - 1;
          unsigned int u = 0;
          if (vrow && (unsigned)wc < 56u) u = rp[(size_t)wc * 4];
          P[c][0] = (int)(u & 0x000F000Fu);
          P[c][1] = (int)((u >> 4) & 0x000F000Fu);
          P[c][2] = (int)((u >> 8) & 0x000F000Fu);
          P[c][3] = (int)((u >> 12) & 0x000F000Fu);
        }
        #pragma unroll
        for (int cw = 0; cw < 3; cw++) {
          uint4 wvv = W4[(dh * 3 + cw) * 48 + gg];
          #pragma unroll
          for (int p = 0; p < 4; p++) {
            acc2[p][0] = pk_mad(wvv.x, P[p + cw][0], acc2[p][0]);
            acc2[p][1] = pk_mad(wvv.y, P[p + cw][1], acc2[p][1]);
            acc2[p][2] = pk_mad(wvv.z, P[p + cw][2], acc2[p][2]);
            acc2[p][3] = pk_mad(wvv.w, P[p + cw][3], acc2[p][3]);
          }
        }
      }
      float Ar[8], Br[8];
      #pragma unroll
      for (int i = 0; i < 8; i++) { Ar[i] = Af[gg * 8 + i]; Br[i] = Bf[gg * 8 + i]; }
      #pragma unroll
      for (int p = 0; p < 4; p++) {
        unsigned int pk = 0;
        #pragma unroll
        for (int j = 0; j < 4; j++) {
          int a = acc2[p][j];
          int lo = (a << 16) >> 16;
          int hi = a >> 16;
          float vl = fmaf((float)lo, Ar[2 * j], Br[2 * j]);
          float vh = fmaf((float)hi, Ar[2 * j + 1], Br[2 * j + 1]);
          unsigned int ql = (unsigned int)fmaxf(fminf(vl, 15.49f), 0.f);
          unsigned int qh = (unsigned int)fmaxf(fminf(vh, 15.49f), 0.f);
          pk |= ql << (4 * j);
          pk |= qh << (4 * j + 16);
        }
        sh[SH_H2 + (q4 * 4 + p) * 50 + gg] = pk;
      }
    }
  }
  __syncthreads();

  // ---- Phase C: conv3 1x1 (384->64) i8 MFMA + bn + act_quant + residual ----
  {
    int wv = tid >> 6, lane = tid & 63;
    int m = lane & 15, quad = lane >> 4;
    const long* sh8 = (const long*)&sh[SH_W3];
    const float* scl = (const float*)&sh[SH_SC3];
    int px_local = wv * 16 + m;

    unsigned int ua[12];
    #pragma unroll
    for (int ks = 0; ks < 12; ks++) ua[ks] = sh[SH_H2 + px_local * 50 + ks * 4 + quad];

    v4i acc3[4];
    #pragma unroll
    for (int nt = 0; nt < 4; nt++) { v4i z = {0, 0, 0, 0}; acc3[nt] = z; }

    #pragma unroll
    for (int ks = 0; ks < 12; ks++) {
      unsigned int u = ua[ks];
      unsigned int tt = u & 0x0F0F0F0Fu;
      unsigned int ss = (u >> 4) & 0x0F0F0F0Fu;
      unsigned int d0 = (tt & 0xFFu) | ((ss & 0xFFu) << 8) | ((tt & 0xFF00u) << 8) | ((ss & 0xFF00u) << 16);
      unsigned int d1 = ((tt >> 16) & 0xFFu) | (((ss >> 16) & 0xFFu) << 8) | ((tt >> 24) << 16) | ((ss >> 24) << 24);
      long aF = (long)(((unsigned long)d1 << 32) | (unsigned long)d0);
      #pragma unroll
      for (int nt = 0; nt < 4; nt++) {
        long bF = sh8[(ks * 4 + nt) * 64 + lane];
        acc3[nt] = __builtin_amdgcn_mfma_i32_16x16x32_i8(aF, bF, acc3[nt], 0, 0, 0);
      }
    }

    int prem = trem * 64 + wv * 16 + quad * 4;
    #pragma unroll
    for (int nt = 0; nt < 4; nt++) {
      int n = nt * 16 + m;
      float sc = scl[n];
      float bi = scl[64 + n];
      size_t off = ((size_t)img * CIN + n) * HW + prem;
      const float4 xv = *(const float4*)(x + off);
      float4 ov;
      float v, a;
      v = (float)acc3[nt][0] * sc + bi; a = fminf(fmaxf(v, 0.f), 1.f); ov.x = rintf(a * 15.f) * INV15 + xv.x;
      v = (float)acc3[nt][1] * sc + bi; a = fminf(fmaxf(v, 0.f), 1.f); ov.y = rintf(a * 15.f) * INV15 + xv.y;
      v = (float)acc3[nt][2] * sc + bi; a = fminf(fmaxf(v, 0.f), 1.f); ov.z = rintf(a * 15.f) * INV15 + xv.z;
      v = (float)acc3[nt][3] * sc + bi; a = fminf(fmaxf(v, 0.f), 1.f); ov.w = rintf(a * 15.f) * INV15 + xv.w;
      *(float4*)(out + off) = ov;
    }
  }
}

extern "C" void kernel_launch(void* const* d_in, const int* in_sizes, int n_in,
                              void* d_out, int out_size, void* d_ws, size_t ws_size,
                              hipStream_t stream) {
  const float* x  = (const float*)d_in[0];
  const float* w1 = (const float*)d_in[1];
  const float* w2 = (const float*)d_in[2];
  const float* w3 = (const float*)d_in[3];
  const float* g1 = (const float*)d_in[4];
  const float* b1 = (const float*)d_in[5];
  const float* m1 = (const float*)d_in[6];
  const float* v1 = (const float*)d_in[7];
  const float* g2 = (const float*)d_in[8];
  const float* b2 = (const float*)d_in[9];
  const float* m2 = (const float*)d_in[10];
  const float* v2 = (const float*)d_in[11];
  const float* g3 = (const float*)d_in[12];
  const float* b3 = (const float*)d_in[13];
  const float* m3 = (const float*)d_in[14];
  const float* v3 = (const float*)d_in[15];

  char* ws = (char*)d_ws;
  unsigned int* maxu = (unsigned int*)(ws + OFF_MAX);
  char* h1b = ws + OFF_H1;
  float* outp = (float*)d_out;

  hipMemsetAsync(maxu, 0, 12, stream);
  prep_max<<<dim3(48), dim3(256), 0, stream>>>(w1, w2, w3, maxu);
  prep_quant<<<dim3(206), dim3(256), 0, stream>>>(
      w1, w2, w3, g1, b1, m1, v1, g2, b2, m2, v2, g3, b3, m3, v3, ws);
  k1<<<dim3(1568), dim3(256), 0, stream>>>(x, ws + OFF_BLOB1, h1b);
  InvertedBottleneck_conv_Q_13709535609694_kernel<<<dim3(1568), dim3(256), 0, stream>>>(
      (const unsigned int*)h1b, ws, x, outp);
}

// Round 10
// 167.792 us; speedup vs baseline: 1.1979x; 1.0075x over previous
//
#include <hip/hip_runtime.h>
#include <hip/hip_bf16.h>

#define EPS 1e-5f
#define INV15 (1.0f/15.0f)

#define CIN 64
#define HID 384
#define HW 3136        // 56*56
#define NPIX 100352    // 32*HW
#define BLKPB 1605632  // NPIX*16 bytes per 32-channel block (packed nibbles)
#define NPIXU4 401408  // NPIX*4 uints per 32-channel block

// ws layout (bytes)
#define OFF_BLOB1 0          // 52224: W1frag bf16 [24mt][2ks][64lane][8e] (49152) + sc15[384]f + bi15[384]f
#define OFF_W2PK 52224       // 6912: W2pk[9tap][48g][4j] packed i16x2 weights
#define OFF_A2   59136       // 1536: A2 = s2/15
#define OFF_B2   60672       // 1536: B2 = 15*b2' + 0.5
#define OFF_BLOB3 62208      // 25088: w3 i8 frags [12ks][4nt][64lane][8j] + scale3[64] + bias3[64]
#define OFF_MAX  87296       // 12: uint-as-float max|w|
#define OFF_H1 1048576       // 12 blocks * BLKPB

// merged-kernel LDS (uint words): 23296 B -> 6 blocks/CU (w3 frags now read from L2)
#define SH_W2 0        // 2496: W2pk 1728 | A2 384 | B2 384
#define SH_SC3 2496    // 128: scale3 | bias3
#define SH_H2 2624     // 64 px * 50 w (padded stride -> conflict-free)
#define SH_TOT 5824

typedef int v4i __attribute__((ext_vector_type(4)));
typedef float f32x4 __attribute__((ext_vector_type(4)));
typedef short bf16x8 __attribute__((ext_vector_type(8)));

__device__ __forceinline__ short splitbf(float f, float& rem) {
  __hip_bfloat16 h = __float2bfloat16(f);
  rem = f - __bfloat162float(h);
  return __builtin_bit_cast(short, h);
}

__device__ __forceinline__ int pk_mad(unsigned int w, int a, int c) {
  int d;
  asm("v_pk_mad_i16 %0, %1, %2, %3" : "=v"(d) : "v"(w), "v"(a), "v"(c));
  return d;
}

// channel of (group g, pair j, half h) in the nibble-packed layout
__device__ __forceinline__ int ch_of(int g, int j, int h) {
  return 32 * (g >> 2) + 4 * (g & 3) + 16 * (j & 1) + ((j >> 1) & 1) + 2 * h;
}

// 48 blocks: max|w| per tensor (max|tanh w| = tanh(max|w|), tanh monotone odd)
__global__ __launch_bounds__(256) void prep_max(
    const float* __restrict__ w1, const float* __restrict__ w2,
    const float* __restrict__ w3, unsigned int* __restrict__ maxout) {
  int b = blockIdx.x >> 4;
  int sub = blockIdx.x & 15;
  const float* src = (b == 0) ? w1 : (b == 1) ? w2 : w3;
  int n = (b == 1) ? HID * 9 : HID * CIN;
  float m = 0.f;
  for (int i = sub * 256 + threadIdx.x; i < n; i += 4096)
    m = fmaxf(m, fabsf(src[i]));
  #pragma unroll
  for (int off = 32; off > 0; off >>= 1)
    m = fmaxf(m, __shfl_down(m, off, 64));
  __shared__ float red[4];
  if ((threadIdx.x & 63) == 0) red[threadIdx.x >> 6] = m;
  __syncthreads();
  if (threadIdx.x == 0) {
    m = fmaxf(fmaxf(red[0], red[1]), fmaxf(red[2], red[3]));
    atomicMax(maxout + b, __float_as_uint(m));
  }
}

// builds all folded/permuted weight blobs. 52544 ids -> 206 blocks.
__global__ __launch_bounds__(256) void prep_quant(
    const float* __restrict__ w1, const float* __restrict__ w2,
    const float* __restrict__ w3,
    const float* __restrict__ g1, const float* __restrict__ b1,
    const float* __restrict__ m1, const float* __restrict__ v1,
    const float* __restrict__ g2, const float* __restrict__ b2,
    const float* __restrict__ m2, const float* __restrict__ v2,
    const float* __restrict__ g3, const float* __restrict__ b3,
    const float* __restrict__ m3, const float* __restrict__ v3,
    char* __restrict__ ws) {
  const float* maxv = (const float*)(ws + OFF_MAX);
  int idx = blockIdx.x * 256 + threadIdx.x;
  if (idx < 24576) {                      // W1frag bf16 (exact odd ints -15..15)
    float mm = tanhf(maxv[0]);
    int e = idx & 7, lane = (idx >> 3) & 63, ks = (idx >> 9) & 1, mt = idx >> 10;
    int o = mt * 16 + (lane & 15);
    int k = ks * 32 + (lane >> 4) * 8 + e;
    float t = tanhf(w1[o * 64 + k]);
    int wi = 2 * (int)rintf((t / (2.f * mm) + 0.5f) * 15.f) - 15;
    float rr;
    ((short*)(ws + OFF_BLOB1))[idx] = splitbf((float)wi, rr);
  } else if (idx < 26304) {               // W2pk packed i16x2 integer weights
    float mm = tanhf(maxv[1]);
    int jj = idx - 24576;
    int tap = jj / 192, rem = jj - tap * 192;
    int g = rem >> 2, j = rem & 3;
    int clo = ch_of(g, j, 0), chi = ch_of(g, j, 1);
    int wlo = 2 * (int)rintf((tanhf(w2[clo * 9 + tap]) / (2.f * mm) + 0.5f) * 15.f) - 15;
    int whi = 2 * (int)rintf((tanhf(w2[chi * 9 + tap]) / (2.f * mm) + 0.5f) * 15.f) - 15;
    ((unsigned int*)(ws + OFF_W2PK))[jj] =
        ((unsigned int)(unsigned short)(short)wlo) |
        (((unsigned int)(unsigned short)(short)whi) << 16);
  } else if (idx < 26688) {               // A2 = s2/15
    int ii = idx - 26304;
    int g = ii >> 3, j = (ii >> 1) & 3, h = ii & 1;
    int c = ch_of(g, j, h);
    float s = g2[c] / sqrtf(v2[c] + EPS);
    ((float*)(ws + OFF_A2))[ii] = s * (1.f / 15.f);
  } else if (idx < 27072) {               // B2 = 15*b2' + 0.5
    int ii = idx - 26688;
    int g = ii >> 3, j = (ii >> 1) & 3, h = ii & 1;
    int c = ch_of(g, j, h);
    float s = g2[c] / sqrtf(v2[c] + EPS);
    ((float*)(ws + OFF_B2))[ii] = 15.f * (b2[c] - m2[c] * s) + 0.5f;
  } else if (idx < 27456) {               // sc15 = s1
    int o = idx - 27072;
    ((float*)(ws + OFF_BLOB1 + 49152))[o] = g1[o] / sqrtf(v1[o] + EPS);
  } else if (idx < 27840) {               // bi15 = 15*(b1 - m1*s1)
    int o = idx - 27456;
    float s = g1[o] / sqrtf(v1[o] + EPS);
    ((float*)(ws + OFF_BLOB1 + 50688))[o] = 15.f * (b1[o] - m1[o] * s);
  } else if (idx < 52416) {               // w3 i8 frags, nibble-permuted k
    float mm = tanhf(maxv[2]);
    int jj = idx - 27840;
    int j = jj & 7, lane = (jj >> 3) & 63, nt = (jj >> 9) & 3, ks = jj >> 11;
    int n = nt * 16 + (lane & 15);
    int quad = lane >> 4;
    int k = ks * 32 + ((j & 1) ? (16 + quad * 4 + (j >> 1)) : (quad * 4 + (j >> 1)));
    float t = tanhf(w3[n * 384 + k]);
    int wi = 2 * (int)rintf((t / (2.f * mm) + 0.5f) * 15.f) - 15;
    (ws + OFF_BLOB3)[jj] = (char)wi;
  } else if (idx < 52480) {               // scale3 = s3/225
    int n = idx - 52416;
    float s = g3[n] / sqrtf(v3[n] + EPS);
    *(float*)(ws + OFF_BLOB3 + 24576 + n * 4) = s * (1.f / 225.f);
  } else if (idx < 52544) {               // bias3
    int n = idx - 52480;
    float s = g3[n] / sqrtf(v3[n] + EPS);
    *(float*)(ws + OFF_BLOB3 + 24832 + n * 4) = b3[n] - m3[n] * s;
  }
}

// conv1 1x1 (64->384) via bf16 MFMA + bn + relu + act_quant -> packed nibbles.
// Weights read directly from L2-hot global blob (coalesced 16 B/lane) — no big LDS,
// so occupancy is VGPR-bound: __launch_bounds__(256,4) ~128-reg cap -> 4 blocks/CU.
__global__ __launch_bounds__(256, 4) void k1(
    const float* __restrict__ x, const char* __restrict__ blob1,
    char* __restrict__ h1b) {
  __shared__ float sSB[768];   // sc15 | bi15
  int tid = threadIdx.x;
  {
    const float* s1 = (const float*)(blob1 + 49152);
    for (int i = tid; i < 768; i += 256) sSB[i] = s1[i];
  }
  __syncthreads();
  const bf16x8* wf = (const bf16x8*)blob1;

  int wv = tid >> 6, lane = tid & 63;
  int quad = lane >> 4, m = lane & 15;

  int grp = blockIdx.x * 4 + wv;                  // 16-px group, 0..6271
  size_t pixabs = (size_t)grp * 16 + m;
  int img = grp / 196;                            // 196 groups per image
  int prem = (grp - img * 196) * 16 + m;
  const float* xb = x + (size_t)img * (CIN * HW) + prem;

  bf16x8 xh[2], xl[2], xq[2];
  #pragma unroll
  for (int ks = 0; ks < 2; ks++) {
    #pragma unroll
    for (int e = 0; e < 8; e++) {
      float f = xb[(size_t)(ks * 32 + quad * 8 + e) * HW];
      float r1, r2, r3;
      xh[ks][e] = splitbf(f, r1);
      xl[ks][e] = splitbf(r1, r2);
      xq[ks][e] = splitbf(r2, r3);
    }
  }

  #pragma unroll
  for (int half = 0; half < 2; half++) {
    f32x4 acc[12];
    #pragma unroll
    for (int i = 0; i < 12; i++) { f32x4 z = {0.f, 0.f, 0.f, 0.f}; acc[i] = z; }
    #pragma unroll
    for (int i = 0; i < 12; i++) {
      int mt = half * 12 + i;
      bf16x8 w0 = wf[(mt * 2 + 0) * 64 + lane];
      bf16x8 w1 = wf[(mt * 2 + 1) * 64 + lane];
      acc[i] = __builtin_amdgcn_mfma_f32_16x16x32_bf16(w0, xh[0], acc[i], 0, 0, 0);
      acc[i] = __builtin_amdgcn_mfma_f32_16x16x32_bf16(w1, xh[1], acc[i], 0, 0, 0);
      acc[i] = __builtin_amdgcn_mfma_f32_16x16x32_bf16(w0, xl[0], acc[i], 0, 0, 0);
      acc[i] = __builtin_amdgcn_mfma_f32_16x16x32_bf16(w1, xl[1], acc[i], 0, 0, 0);
      acc[i] = __builtin_amdgcn_mfma_f32_16x16x32_bf16(w0, xq[0], acc[i], 0, 0, 0);
      acc[i] = __builtin_amdgcn_mfma_f32_16x16x32_bf16(w1, xq[1], acc[i], 0, 0, 0);
    }
    #pragma unroll
    for (int l = 0; l < 6; l++) {
      int b = half * 6 + l;
      f32x4 ae = acc[2 * l], ao = acc[2 * l + 1];
      unsigned int pk = 0;
      #pragma unroll
      for (int r = 0; r < 4; r++) {
        int oe = 32 * b + quad * 4 + r;
        int oo = oe + 16;
        float fe = fminf(fmaxf(ae[r] * sSB[oe] + sSB[384 + oe], 0.f), 15.f);
        float fo = fminf(fmaxf(ao[r] * sSB[oo] + sSB[384 + oo], 0.f), 15.f);
        pk |= ((unsigned int)(int)rintf(fe)) << (8 * r);
        pk |= ((unsigned int)(int)rintf(fo)) << (8 * r + 4);
      }
      *(unsigned int*)(h1b + (size_t)b * BLKPB + pixabs * 16 + quad * 4) = pk;
    }
  }
}

// Merged dw3x3(pk_mad, h2 -> LDS) + conv3(i8 MFMA, w3 frags from L2) + residual.
// grid 1568: one block = 64 px of one image. 23 KB LDS -> 6 blocks/CU.
__global__ __launch_bounds__(256, 6) void InvertedBottleneck_conv_Q_13709535609694_kernel(
    const unsigned int* __restrict__ h1q, const char* __restrict__ ws,
    const float* __restrict__ x, float* __restrict__ out) {
  __shared__ unsigned int sh[SH_TOT];
  int tid = threadIdx.x;
  {
    const unsigned int* s2 = (const unsigned int*)(ws + OFF_W2PK);
    for (int i = tid; i < 2496; i += 256) sh[SH_W2 + i] = s2[i];
    const unsigned int* s3 = (const unsigned int*)(ws + OFF_BLOB3 + 24576);
    if (tid < 128) sh[SH_SC3 + tid] = s3[tid];
  }
  __syncthreads();

  int img = blockIdx.x / 49;
  int trem = blockIdx.x - img * 49;
  size_t imgrow = (size_t)img * HW;

  // ---- Phase B: depthwise 3x3 via pk_mad -> h2 tile in LDS ----
  {
    const uint4* W4 = (const uint4*)&sh[SH_W2];
    const float* Af = (const float*)&sh[SH_W2 + 1728];
    const float* Bf = Af + 384;
    #pragma unroll
    for (int it2 = 0; it2 < 3; it2++) {
      int id = it2 * 256 + tid;          // 768 = 48 g x 16 quads
      int gg = id % 48, q4 = id / 48;
      int prem = trem * 64 + q4 * 4;
      int h = prem / 56, w0 = prem - h * 56;   // 4-px quad never crosses a row (56%4==0)
      size_t base_u = (size_t)(gg >> 2) * NPIXU4 + (gg & 3);
      int acc2[4][4];
      #pragma unroll
      for (int p = 0; p < 4; p++)
        #pragma unroll
        for (int j = 0; j < 4; j++) acc2[p][j] = 0;
      #pragma unroll
      for (int dh = 0; dh < 3; dh++) {
        int hr = h + dh - 1;
        bool vrow = (unsigned)hr < 56u;
        const unsigned int* rp = h1q + base_u + (imgrow + (size_t)hr * 56) * 4;
        int P[6][4];
        #pragma unroll
        for (int c = 0; c < 6; c++) {
          int wc = w0 + c - 1;
          unsigned int u = 0;
          if (vrow && (unsigned)wc < 56u) u = rp[(size_t)wc * 4];
          P[c][0] = (int)(u & 0x000F000Fu);
          P[c][1] = (int)((u >> 4) & 0x000F000Fu);
          P[c][2] = (int)((u >> 8) & 0x000F000Fu);
          P[c][3] = (int)((u >> 12) & 0x000F000Fu);
        }
        #pragma unroll
        for (int cw = 0; cw < 3; cw++) {
          uint4 wvv = W4[(dh * 3 + cw) * 48 + gg];
          #pragma unroll
          for (int p = 0; p < 4; p++) {
            acc2[p][0] = pk_mad(wvv.x, P[p + cw][0], acc2[p][0]);
            acc2[p][1] = pk_mad(wvv.y, P[p + cw][1], acc2[p][1]);
            acc2[p][2] = pk_mad(wvv.z, P[p + cw][2], acc2[p][2]);
            acc2[p][3] = pk_mad(wvv.w, P[p + cw][3], acc2[p][3]);
          }
        }
      }
      float Ar[8], Br[8];
      #pragma unroll
      for (int i = 0; i < 8; i++) { Ar[i] = Af[gg * 8 + i]; Br[i] = Bf[gg * 8 + i]; }
      #pragma unroll
      for (int p = 0; p < 4; p++) {
        unsigned int pk = 0;
        #pragma unroll
        for (int j = 0; j < 4; j++) {
          int a = acc2[p][j];
          int lo = (a << 16) >> 16;
          int hi = a >> 16;
          float vl = fmaf((float)lo, Ar[2 * j], Br[2 * j]);
          float vh = fmaf((float)hi, Ar[2 * j + 1], Br[2 * j + 1]);
          unsigned int ql = (unsigned int)fmaxf(fminf(vl, 15.49f), 0.f);
          unsigned int qh = (unsigned int)fmaxf(fminf(vh, 15.49f), 0.f);
          pk |= ql << (4 * j);
          pk |= qh << (4 * j + 16);
        }
        sh[SH_H2 + (q4 * 4 + p) * 50 + gg] = pk;
      }
    }
  }
  __syncthreads();

  // ---- Phase C: conv3 1x1 (384->64) i8 MFMA (w3 frags from L2) + residual ----
  {
    int wv = tid >> 6, lane = tid & 63;
    int m = lane & 15, quad = lane >> 4;
    const long* w3g = (const long*)(ws + OFF_BLOB3);
    const float* scl = (const float*)&sh[SH_SC3];
    int px_local = wv * 16 + m;

    unsigned int ua[12];
    #pragma unroll
    for (int ks = 0; ks < 12; ks++) ua[ks] = sh[SH_H2 + px_local * 50 + ks * 4 + quad];

    v4i acc3[4];
    #pragma unroll
    for (int nt = 0; nt < 4; nt++) { v4i z = {0, 0, 0, 0}; acc3[nt] = z; }

    #pragma unroll
    for (int ks = 0; ks < 12; ks++) {
      unsigned int u = ua[ks];
      unsigned int tt = u & 0x0F0F0F0Fu;
      unsigned int ss = (u >> 4) & 0x0F0F0F0Fu;
      unsigned int d0 = (tt & 0xFFu) | ((ss & 0xFFu) << 8) | ((tt & 0xFF00u) << 8) | ((ss & 0xFF00u) << 16);
      unsigned int d1 = ((tt >> 16) & 0xFFu) | (((ss >> 16) & 0xFFu) << 8) | ((tt >> 24) << 16) | ((ss >> 24) << 24);
      long aF = (long)(((unsigned long)d1 << 32) | (unsigned long)d0);
      #pragma unroll
      for (int nt = 0; nt < 4; nt++) {
        long bF = w3g[(ks * 4 + nt) * 64 + lane];
        acc3[nt] = __builtin_amdgcn_mfma_i32_16x16x32_i8(aF, bF, acc3[nt], 0, 0, 0);
      }
    }

    int prem = trem * 64 + wv * 16 + quad * 4;
    #pragma unroll
    for (int nt = 0; nt < 4; nt++) {
      int n = nt * 16 + m;
      float sc = scl[n];
      float bi = scl[64 + n];
      size_t off = ((size_t)img * CIN + n) * HW + prem;
      const float4 xv = *(const float4*)(x + off);
      float4 ov;
      float v, a;
      v = (float)acc3[nt][0] * sc + bi; a = fminf(fmaxf(v, 0.f), 1.f); ov.x = rintf(a * 15.f) * INV15 + xv.x;
      v = (float)acc3[nt][1] * sc + bi; a = fminf(fmaxf(v, 0.f), 1.f); ov.y = rintf(a * 15.f) * INV15 + xv.y;
      v = (float)acc3[nt][2] * sc + bi; a = fminf(fmaxf(v, 0.f), 1.f); ov.z = rintf(a * 15.f) * INV15 + xv.z;
      v = (float)acc3[nt][3] * sc + bi; a = fminf(fmaxf(v, 0.f), 1.f); ov.w = rintf(a * 15.f) * INV15 + xv.w;
      *(float4*)(out + off) = ov;
    }
  }
}

extern "C" void kernel_launch(void* const* d_in, const int* in_sizes, int n_in,
                              void* d_out, int out_size, void* d_ws, size_t ws_size,
                              hipStream_t stream) {
  const float* x  = (const float*)d_in[0];
  const float* w1 = (const float*)d_in[1];
  const float* w2 = (const float*)d_in[2];
  const float* w3 = (const float*)d_in[3];
  const float* g1 = (const float*)d_in[4];
  const float* b1 = (const float*)d_in[5];
  const float* m1 = (const float*)d_in[6];
  const float* v1 = (const float*)d_in[7];
  const float* g2 = (const float*)d_in[8];
  const float* b2 = (const float*)d_in[9];
  const float* m2 = (const float*)d_in[10];
  const float* v2 = (const float*)d_in[11];
  const float* g3 = (const float*)d_in[12];
  const float* b3 = (const float*)d_in[13];
  const float* m3 = (const float*)d_in[14];
  const float* v3 = (const float*)d_in[15];

  char* ws = (char*)d_ws;
  unsigned int* maxu = (unsigned int*)(ws + OFF_MAX);
  char* h1b = ws + OFF_H1;
  float* outp = (float*)d_out;

  hipMemsetAsync(maxu, 0, 12, stream);
  prep_max<<<dim3(48), dim3(256), 0, stream>>>(w1, w2, w3, maxu);
  prep_quant<<<dim3(206), dim3(256), 0, stream>>>(
      w1, w2, w3, g1, b1, m1, v1, g2, b2, m2, v2, g3, b3, m3, v3, ws);
  k1<<<dim3(1568), dim3(256), 0, stream>>>(x, ws + OFF_BLOB1, h1b);
  InvertedBottleneck_conv_Q_13709535609694_kernel<<<dim3(1568), dim3(256), 0, stream>>>(
      (const unsigned int*)h1b, ws, x, outp);
}

// Round 11
// 167.156 us; speedup vs baseline: 1.2024x; 1.0038x over previous
//
#include <hip/hip_runtime.h>
#include <hip/hip_bf16.h>

#define EPS 1e-5f
#define INV15 (1.0f/15.0f)

#define CIN 64
#define HID 384
#define HW 3136        // 56*56
#define NPIX 100352    // 32*HW
#define BLKPB 1605632  // NPIX*16 bytes per 32-channel block (packed nibbles)
#define NPIXU4 401408  // NPIX*4 uints per 32-channel block

// ws layout (bytes)
#define OFF_BLOB1 0          // 52224: W1frag bf16 [24mt][2ks][64lane][8e] (49152) + sc15[384]f + bi15[384]f
#define OFF_W2PK 52224       // 6912: W2pk[9tap][48g][4j] packed i16x2 weights
#define OFF_A2   59136       // 1536: A2 = s2/15
#define OFF_B2   60672       // 1536: B2 = 15*b2' + 0.5
#define OFF_BLOB3 62208      // 25088: w3 i8 frags [12ks][4nt][64lane][8j] + scale3[64] + bias3[64]
#define OFF_MAX  87296       // 12: uint-as-float max|w|
#define OFF_H1 1048576       // 12 blocks * BLKPB

// merged-kernel LDS (uint words): 23296 B -> LDS permits 6 blocks/CU
#define SH_W2 0        // 2496: W2pk 1728 | A2 384 | B2 384
#define SH_SC3 2496    // 128: scale3 | bias3
#define SH_H2 2624     // 64 px * 50 w (padded stride -> conflict-free)
#define SH_TOT 5824

typedef int v4i __attribute__((ext_vector_type(4)));
typedef float f32x4 __attribute__((ext_vector_type(4)));
typedef short bf16x8 __attribute__((ext_vector_type(8)));

__device__ __forceinline__ short splitbf(float f, float& rem) {
  __hip_bfloat16 h = __float2bfloat16(f);
  rem = f - __bfloat162float(h);
  return __builtin_bit_cast(short, h);
}

__device__ __forceinline__ int pk_mad(unsigned int w, int a, int c) {
  int d;
  asm("v_pk_mad_i16 %0, %1, %2, %3" : "=v"(d) : "v"(w), "v"(a), "v"(c));
  return d;
}

// channel of (group g, pair j, half h) in the nibble-packed layout
__device__ __forceinline__ int ch_of(int g, int j, int h) {
  return 32 * (g >> 2) + 4 * (g & 3) + 16 * (j & 1) + ((j >> 1) & 1) + 2 * h;
}

// 48 blocks: max|w| per tensor (max|tanh w| = tanh(max|w|), tanh monotone odd)
__global__ __launch_bounds__(256) void prep_max(
    const float* __restrict__ w1, const float* __restrict__ w2,
    const float* __restrict__ w3, unsigned int* __restrict__ maxout) {
  int b = blockIdx.x >> 4;
  int sub = blockIdx.x & 15;
  const float* src = (b == 0) ? w1 : (b == 1) ? w2 : w3;
  int n = (b == 1) ? HID * 9 : HID * CIN;
  float m = 0.f;
  for (int i = sub * 256 + threadIdx.x; i < n; i += 4096)
    m = fmaxf(m, fabsf(src[i]));
  #pragma unroll
  for (int off = 32; off > 0; off >>= 1)
    m = fmaxf(m, __shfl_down(m, off, 64));
  __shared__ float red[4];
  if ((threadIdx.x & 63) == 0) red[threadIdx.x >> 6] = m;
  __syncthreads();
  if (threadIdx.x == 0) {
    m = fmaxf(fmaxf(red[0], red[1]), fmaxf(red[2], red[3]));
    atomicMax(maxout + b, __float_as_uint(m));
  }
}

// builds all folded/permuted weight blobs. 52544 ids -> 206 blocks.
__global__ __launch_bounds__(256) void prep_quant(
    const float* __restrict__ w1, const float* __restrict__ w2,
    const float* __restrict__ w3,
    const float* __restrict__ g1, const float* __restrict__ b1,
    const float* __restrict__ m1, const float* __restrict__ v1,
    const float* __restrict__ g2, const float* __restrict__ b2,
    const float* __restrict__ m2, const float* __restrict__ v2,
    const float* __restrict__ g3, const float* __restrict__ b3,
    const float* __restrict__ m3, const float* __restrict__ v3,
    char* __restrict__ ws) {
  const float* maxv = (const float*)(ws + OFF_MAX);
  int idx = blockIdx.x * 256 + threadIdx.x;
  if (idx < 24576) {                      // W1frag bf16 (exact odd ints -15..15)
    float mm = tanhf(maxv[0]);
    int e = idx & 7, lane = (idx >> 3) & 63, ks = (idx >> 9) & 1, mt = idx >> 10;
    int o = mt * 16 + (lane & 15);
    int k = ks * 32 + (lane >> 4) * 8 + e;
    float t = tanhf(w1[o * 64 + k]);
    int wi = 2 * (int)rintf((t / (2.f * mm) + 0.5f) * 15.f) - 15;
    float rr;
    ((short*)(ws + OFF_BLOB1))[idx] = splitbf((float)wi, rr);
  } else if (idx < 26304) {               // W2pk packed i16x2 integer weights
    float mm = tanhf(maxv[1]);
    int jj = idx - 24576;
    int tap = jj / 192, rem = jj - tap * 192;
    int g = rem >> 2, j = rem & 3;
    int clo = ch_of(g, j, 0), chi = ch_of(g, j, 1);
    int wlo = 2 * (int)rintf((tanhf(w2[clo * 9 + tap]) / (2.f * mm) + 0.5f) * 15.f) - 15;
    int whi = 2 * (int)rintf((tanhf(w2[chi * 9 + tap]) / (2.f * mm) + 0.5f) * 15.f) - 15;
    ((unsigned int*)(ws + OFF_W2PK))[jj] =
        ((unsigned int)(unsigned short)(short)wlo) |
        (((unsigned int)(unsigned short)(short)whi) << 16);
  } else if (idx < 26688) {               // A2 = s2/15
    int ii = idx - 26304;
    int g = ii >> 3, j = (ii >> 1) & 3, h = ii & 1;
    int c = ch_of(g, j, h);
    float s = g2[c] / sqrtf(v2[c] + EPS);
    ((float*)(ws + OFF_A2))[ii] = s * (1.f / 15.f);
  } else if (idx < 27072) {               // B2 = 15*b2' + 0.5
    int ii = idx - 26688;
    int g = ii >> 3, j = (ii >> 1) & 3, h = ii & 1;
    int c = ch_of(g, j, h);
    float s = g2[c] / sqrtf(v2[c] + EPS);
    ((float*)(ws + OFF_B2))[ii] = 15.f * (b2[c] - m2[c] * s) + 0.5f;
  } else if (idx < 27456) {               // sc15 = s1
    int o = idx - 27072;
    ((float*)(ws + OFF_BLOB1 + 49152))[o] = g1[o] / sqrtf(v1[o] + EPS);
  } else if (idx < 27840) {               // bi15 = 15*(b1 - m1*s1)
    int o = idx - 27456;
    float s = g1[o] / sqrtf(v1[o] + EPS);
    ((float*)(ws + OFF_BLOB1 + 50688))[o] = 15.f * (b1[o] - m1[o] * s);
  } else if (idx < 52416) {               // w3 i8 frags, nibble-permuted k
    float mm = tanhf(maxv[2]);
    int jj = idx - 27840;
    int j = jj & 7, lane = (jj >> 3) & 63, nt = (jj >> 9) & 3, ks = jj >> 11;
    int n = nt * 16 + (lane & 15);
    int quad = lane >> 4;
    int k = ks * 32 + ((j & 1) ? (16 + quad * 4 + (j >> 1)) : (quad * 4 + (j >> 1)));
    float t = tanhf(w3[n * 384 + k]);
    int wi = 2 * (int)rintf((t / (2.f * mm) + 0.5f) * 15.f) - 15;
    (ws + OFF_BLOB3)[jj] = (char)wi;
  } else if (idx < 52480) {               // scale3 = s3/225
    int n = idx - 52416;
    float s = g3[n] / sqrtf(v3[n] + EPS);
    *(float*)(ws + OFF_BLOB3 + 24576 + n * 4) = s * (1.f / 225.f);
  } else if (idx < 52544) {               // bias3
    int n = idx - 52480;
    float s = g3[n] / sqrtf(v3[n] + EPS);
    *(float*)(ws + OFF_BLOB3 + 24832 + n * 4) = b3[n] - m3[n] * s;
  }
}

// conv1 1x1 (64->384) via bf16 MFMA + bn + relu + act_quant -> packed nibbles.
// Weights read directly from L2-hot global blob (coalesced 16 B/lane) — no big LDS.
__global__ __launch_bounds__(256, 4) void k1(
    const float* __restrict__ x, const char* __restrict__ blob1,
    char* __restrict__ h1b) {
  __shared__ float sSB[768];   // sc15 | bi15
  int tid = threadIdx.x;
  {
    const float* s1 = (const float*)(blob1 + 49152);
    for (int i = tid; i < 768; i += 256) sSB[i] = s1[i];
  }
  __syncthreads();
  const bf16x8* wf = (const bf16x8*)blob1;

  int wv = tid >> 6, lane = tid & 63;
  int quad = lane >> 4, m = lane & 15;

  int grp = blockIdx.x * 4 + wv;                  // 16-px group, 0..6271
  size_t pixabs = (size_t)grp * 16 + m;
  int img = grp / 196;                            // 196 groups per image
  int prem = (grp - img * 196) * 16 + m;
  const float* xb = x + (size_t)img * (CIN * HW) + prem;

  bf16x8 xh[2], xl[2], xq[2];
  #pragma unroll
  for (int ks = 0; ks < 2; ks++) {
    #pragma unroll
    for (int e = 0; e < 8; e++) {
      float f = xb[(size_t)(ks * 32 + quad * 8 + e) * HW];
      float r1, r2, r3;
      xh[ks][e] = splitbf(f, r1);
      xl[ks][e] = splitbf(r1, r2);
      xq[ks][e] = splitbf(r2, r3);
    }
  }

  #pragma unroll
  for (int half = 0; half < 2; half++) {
    f32x4 acc[12];
    #pragma unroll
    for (int i = 0; i < 12; i++) { f32x4 z = {0.f, 0.f, 0.f, 0.f}; acc[i] = z; }
    #pragma unroll
    for (int i = 0; i < 12; i++) {
      int mt = half * 12 + i;
      bf16x8 w0 = wf[(mt * 2 + 0) * 64 + lane];
      bf16x8 w1 = wf[(mt * 2 + 1) * 64 + lane];
      acc[i] = __builtin_amdgcn_mfma_f32_16x16x32_bf16(w0, xh[0], acc[i], 0, 0, 0);
      acc[i] = __builtin_amdgcn_mfma_f32_16x16x32_bf16(w1, xh[1], acc[i], 0, 0, 0);
      acc[i] = __builtin_amdgcn_mfma_f32_16x16x32_bf16(w0, xl[0], acc[i], 0, 0, 0);
      acc[i] = __builtin_amdgcn_mfma_f32_16x16x32_bf16(w1, xl[1], acc[i], 0, 0, 0);
      acc[i] = __builtin_amdgcn_mfma_f32_16x16x32_bf16(w0, xq[0], acc[i], 0, 0, 0);
      acc[i] = __builtin_amdgcn_mfma_f32_16x16x32_bf16(w1, xq[1], acc[i], 0, 0, 0);
    }
    #pragma unroll
    for (int l = 0; l < 6; l++) {
      int b = half * 6 + l;
      f32x4 ae = acc[2 * l], ao = acc[2 * l + 1];
      unsigned int pk = 0;
      #pragma unroll
      for (int r = 0; r < 4; r++) {
        int oe = 32 * b + quad * 4 + r;
        int oo = oe + 16;
        float fe = fminf(fmaxf(ae[r] * sSB[oe] + sSB[384 + oe], 0.f), 15.f);
        float fo = fminf(fmaxf(ao[r] * sSB[oo] + sSB[384 + oo], 0.f), 15.f);
        pk |= ((unsigned int)(int)rintf(fe)) << (8 * r);
        pk |= ((unsigned int)(int)rintf(fo)) << (8 * r + 4);
      }
      *(unsigned int*)(h1b + (size_t)b * BLKPB + pixabs * 16 + quad * 4) = pk;
    }
  }
}

// Merged dw3x3(pk_mad, h2 -> LDS) + conv3(i8 MFMA, w3 frags from L2) + residual.
// grid 1568: one block = 64 px of one image. 23 KB LDS; (256,4) = 128-reg cap:
// R10's (256,6) forced 85-reg cap -> allocator hit 36 VGPR -> scratch spills
// (dur 49->64, VALUBusy 41->31). 128 restores R9's spill-free ~68-VGPR codegen
// while LDS now permits 6 blocks/CU.
__global__ __launch_bounds__(256, 4) void InvertedBottleneck_conv_Q_13709535609694_kernel(
    const unsigned int* __restrict__ h1q, const char* __restrict__ ws,
    const float* __restrict__ x, float* __restrict__ out) {
  __shared__ unsigned int sh[SH_TOT];
  int tid = threadIdx.x;
  {
    const unsigned int* s2 = (const unsigned int*)(ws + OFF_W2PK);
    for (int i = tid; i < 2496; i += 256) sh[SH_W2 + i] = s2[i];
    const unsigned int* s3 = (const unsigned int*)(ws + OFF_BLOB3 + 24576);
    if (tid < 128) sh[SH_SC3 + tid] = s3[tid];
  }
  __syncthreads();

  int img = blockIdx.x / 49;
  int trem = blockIdx.x - img * 49;
  size_t imgrow = (size_t)img * HW;

  // ---- Phase B: depthwise 3x3 via pk_mad -> h2 tile in LDS ----
  {
    const uint4* W4 = (const uint4*)&sh[SH_W2];
    const float* Af = (const float*)&sh[SH_W2 + 1728];
    const float* Bf = Af + 384;
    #pragma unroll
    for (int it2 = 0; it2 < 3; it2++) {
      int id = it2 * 256 + tid;          // 768 = 48 g x 16 quads
      int gg = id % 48, q4 = id / 48;
      int prem = trem * 64 + q4 * 4;
      int h = prem / 56, w0 = prem - h * 56;   // 4-px quad never crosses a row (56%4==0)
      size_t base_u = (size_t)(gg >> 2) * NPIXU4 + (gg & 3);
      int acc2[4][4];
      #pragma unroll
      for (int p = 0; p < 4; p++)
        #pragma unroll
        for (int j = 0; j < 4; j++) acc2[p][j] = 0;
      #pragma unroll
      for (int dh = 0; dh < 3; dh++) {
        int hr = h + dh - 1;
        bool vrow = (unsigned)hr < 56u;
        const unsigned int* rp = h1q + base_u + (imgrow + (size_t)hr * 56) * 4;
        int P[6][4];
        #pragma unroll
        for (int c = 0; c < 6; c++) {
          int wc = w0 + c - 1;
          unsigned int u = 0;
          if (vrow && (unsigned)wc < 56u) u = rp[(size_t)wc * 4];
          P[c][0] = (int)(u & 0x000F000Fu);
          P[c][1] = (int)((u >> 4) & 0x000F000Fu);
          P[c][2] = (int)((u >> 8) & 0x000F000Fu);
          P[c][3] = (int)((u >> 12) & 0x000F000Fu);
        }
        #pragma unroll
        for (int cw = 0; cw < 3; cw++) {
          uint4 wvv = W4[(dh * 3 + cw) * 48 + gg];
          #pragma unroll
          for (int p = 0; p < 4; p++) {
            acc2[p][0] = pk_mad(wvv.x, P[p + cw][0], acc2[p][0]);
            acc2[p][1] = pk_mad(wvv.y, P[p + cw][1], acc2[p][1]);
            acc2[p][2] = pk_mad(wvv.z, P[p + cw][2], acc2[p][2]);
            acc2[p][3] = pk_mad(wvv.w, P[p + cw][3], acc2[p][3]);
          }
        }
      }
      float Ar[8], Br[8];
      #pragma unroll
      for (int i = 0; i < 8; i++) { Ar[i] = Af[gg * 8 + i]; Br[i] = Bf[gg * 8 + i]; }
      #pragma unroll
      for (int p = 0; p < 4; p++) {
        unsigned int pk = 0;
        #pragma unroll
        for (int j = 0; j < 4; j++) {
          int a = acc2[p][j];
          int lo = (a << 16) >> 16;
          int hi = a >> 16;
          float vl = fmaf((float)lo, Ar[2 * j], Br[2 * j]);
          float vh = fmaf((float)hi, Ar[2 * j + 1], Br[2 * j + 1]);
          unsigned int ql = (unsigned int)fmaxf(fminf(vl, 15.49f), 0.f);
          unsigned int qh = (unsigned int)fmaxf(fminf(vh, 15.49f), 0.f);
          pk |= ql << (4 * j);
          pk |= qh << (4 * j + 16);
        }
        sh[SH_H2 + (q4 * 4 + p) * 50 + gg] = pk;
      }
    }
  }
  __syncthreads();

  // ---- Phase C: conv3 1x1 (384->64) i8 MFMA (w3 frags from L2) + residual ----
  {
    int wv = tid >> 6, lane = tid & 63;
    int m = lane & 15, quad = lane >> 4;
    const long* w3g = (const long*)(ws + OFF_BLOB3);
    const float* scl = (const float*)&sh[SH_SC3];
    int px_local = wv * 16 + m;

    unsigned int ua[12];
    #pragma unroll
    for (int ks = 0; ks < 12; ks++) ua[ks] = sh[SH_H2 + px_local * 50 + ks * 4 + quad];

    v4i acc3[4];
    #pragma unroll
    for (int nt = 0; nt < 4; nt++) { v4i z = {0, 0, 0, 0}; acc3[nt] = z; }

    #pragma unroll
    for (int ks = 0; ks < 12; ks++) {
      unsigned int u = ua[ks];
      unsigned int tt = u & 0x0F0F0F0Fu;
      unsigned int ss = (u >> 4) & 0x0F0F0F0Fu;
      unsigned int d0 = (tt & 0xFFu) | ((ss & 0xFFu) << 8) | ((tt & 0xFF00u) << 8) | ((ss & 0xFF00u) << 16);
      unsigned int d1 = ((tt >> 16) & 0xFFu) | (((ss >> 16) & 0xFFu) << 8) | ((tt >> 24) << 16) | ((ss >> 24) << 24);
      long aF = (long)(((unsigned long)d1 << 32) | (unsigned long)d0);
      #pragma unroll
      for (int nt = 0; nt < 4; nt++) {
        long bF = w3g[(ks * 4 + nt) * 64 + lane];
        acc3[nt] = __builtin_amdgcn_mfma_i32_16x16x32_i8(aF, bF, acc3[nt], 0, 0, 0);
      }
    }

    int prem = trem * 64 + wv * 16 + quad * 4;
    #pragma unroll
    for (int nt = 0; nt < 4; nt++) {
      int n = nt * 16 + m;
      float sc = scl[n];
      float bi = scl[64 + n];
      size_t off = ((size_t)img * CIN + n) * HW + prem;
      const float4 xv = *(const float4*)(x + off);
      float4 ov;
      float v, a;
      v = (float)acc3[nt][0] * sc + bi; a = fminf(fmaxf(v, 0.f), 1.f); ov.x = rintf(a * 15.f) * INV15 + xv.x;
      v = (float)acc3[nt][1] * sc + bi; a = fminf(fmaxf(v, 0.f), 1.f); ov.y = rintf(a * 15.f) * INV15 + xv.y;
      v = (float)acc3[nt][2] * sc + bi; a = fminf(fmaxf(v, 0.f), 1.f); ov.z = rintf(a * 15.f) * INV15 + xv.z;
      v = (float)acc3[nt][3] * sc + bi; a = fminf(fmaxf(v, 0.f), 1.f); ov.w = rintf(a * 15.f) * INV15 + xv.w;
      *(float4*)(out + off) = ov;
    }
  }
}

extern "C" void kernel_launch(void* const* d_in, const int* in_sizes, int n_in,
                              void* d_out, int out_size, void* d_ws, size_t ws_size,
                              hipStream_t stream) {
  const float* x  = (const float*)d_in[0];
  const float* w1 = (const float*)d_in[1];
  const float* w2 = (const float*)d_in[2];
  const float* w3 = (const float*)d_in[3];
  const float* g1 = (const float*)d_in[4];
  const float* b1 = (const float*)d_in[5];
  const float* m1 = (const float*)d_in[6];
  const float* v1 = (const float*)d_in[7];
  const float* g2 = (const float*)d_in[8];
  const float* b2 = (const float*)d_in[9];
  const float* m2 = (const float*)d_in[10];
  const float* v2 = (const float*)d_in[11];
  const float* g3 = (const float*)d_in[12];
  const float* b3 = (const float*)d_in[13];
  const float* m3 = (const float*)d_in[14];
  const float* v3 = (const float*)d_in[15];

  char* ws = (char*)d_ws;
  unsigned int* maxu = (unsigned int*)(ws + OFF_MAX);
  char* h1b = ws + OFF_H1;
  float* outp = (float*)d_out;

  hipMemsetAsync(maxu, 0, 12, stream);
  prep_max<<<dim3(48), dim3(256), 0, stream>>>(w1, w2, w3, maxu);
  prep_quant<<<dim3(206), dim3(256), 0, stream>>>(
      w1, w2, w3, g1, b1, m1, v1, g2, b2, m2, v2, g3, b3, m3, v3, ws);
  k1<<<dim3(1568), dim3(256), 0, stream>>>(x, ws + OFF_BLOB1, h1b);
  InvertedBottleneck_conv_Q_13709535609694_kernel<<<dim3(1568), dim3(256), 0, stream>>>(
      (const unsigned int*)h1b, ws, x, outp);
}